// Round 2
// baseline (678.443 us; speedup 1.0000x reference)
//
#include <hip/hip_runtime.h>
#include <cstdint>

typedef unsigned short u16;
typedef unsigned int u32;
typedef float floatx4 __attribute__((ext_vector_type(4)));
typedef __bf16 bf16x8 __attribute__((ext_vector_type(8)));
typedef u16 u16x4 __attribute__((ext_vector_type(4)));

__device__ __forceinline__ u16 f2b(float f) {
  u32 u = __builtin_bit_cast(u32, f);
  u32 r = (u + 0x7fffu + ((u >> 16) & 1u)) >> 16;
  return (u16)r;
}
__device__ __forceinline__ float b2f(u16 b) {
  return __builtin_bit_cast(float, (u32)b << 16);
}
__device__ __forceinline__ float sigf(float x) { return 1.f / (1.f + __expf(-x)); }
__device__ __forceinline__ float tanhfast(float x) { return 2.f / (1.f + __expf(-2.f * x)) - 1.f; }

#define GLDS(gp, lp) __builtin_amdgcn_global_load_lds( \
    (const __attribute__((address_space(1))) u32*)(gp), \
    (__attribute__((address_space(3))) u32*)(lp), 16, 0, 0)

struct GemmArgs {
  const u16* A;  // [M,K] bf16 K-contig
  const u16* W;  // [N,K] bf16 K-contig
  u16* C;        // [M,N] bf16
  int K;
  float* ssum;
  float* ssq;
};

// Transposed-D orientation: acc[i][j] = mfma(W_frag, A_frag) so that
// lane fr = batch row, quad*4+reg = contiguous feature cols -> u16x4 stores.
__device__ __forceinline__ void gemm_body(const GemmArgs g, int N,
                                          u16* As, u16* Bs) {
  const int tid = threadIdx.x;
  const int lane = tid & 63;
  const int wave = tid >> 6;
  const int wm = (wave >> 1) << 6;
  const int wn = (wave & 1) << 6;
  const int m0 = blockIdx.y * 128;
  const int n0 = blockIdx.x * 128;
  const int K = g.K;
  const u16* Ab = g.A + (size_t)m0 * K;
  const u16* Wb = g.W + (size_t)n0 * K;
  const size_t soff = (size_t)(tid >> 2) * K + ((tid & 3) << 3);
  const size_t soff2 = soff + (size_t)64 * K;
  const int fr = lane & 15;  // batch row within 16-block
  const int fq = lane >> 4;  // quad -> feature sub-block
  const int aoff = fr * 32 + fq * 8;

  floatx4 acc[4][4] = {};

  for (int k0 = 0; k0 < K; k0 += 32) {
    __syncthreads();
    GLDS(Ab + soff + k0, &As[tid * 8]);
    GLDS(Ab + soff2 + k0, &As[tid * 8 + 2048]);
    GLDS(Wb + soff + k0, &Bs[tid * 8]);
    GLDS(Wb + soff2 + k0, &Bs[tid * 8 + 2048]);
    __syncthreads();
    bf16x8 af[4], bfv[4];
#pragma unroll
    for (int i = 0; i < 4; ++i) af[i] = *(const bf16x8*)&As[(wm + i * 16) * 32 + aoff];
#pragma unroll
    for (int j = 0; j < 4; ++j) bfv[j] = *(const bf16x8*)&Bs[(wn + j * 16) * 32 + aoff];
#pragma unroll
    for (int i = 0; i < 4; ++i)
#pragma unroll
      for (int j = 0; j < 4; ++j)
        acc[i][j] = __builtin_amdgcn_mfma_f32_16x16x32_bf16(bfv[j], af[i], acc[i][j], 0, 0, 0);
  }

  // C stores: per (i,j) 4 contiguous feature cols -> one 8B store
  u16* C = g.C;
#pragma unroll
  for (int i = 0; i < 4; ++i) {
    const size_t row = (size_t)(m0 + wm + i * 16 + fr);
#pragma unroll
    for (int j = 0; j < 4; ++j) {
      const int cb = n0 + wn + j * 16 + fq * 4;
      u16x4 pk;
#pragma unroll
      for (int r = 0; r < 4; ++r) pk[r] = f2b(acc[i][j][r]);
      *(u16x4*)&C[row * N + cb] = pk;
    }
  }

  // per-column sum / sumsq: reduce over batch (i regs + 16 fr lanes)
#pragma unroll
  for (int j = 0; j < 4; ++j) {
    const int cb = n0 + wn + j * 16 + fq * 4;
    floatx4 s = {}, q = {};
#pragma unroll
    for (int i = 0; i < 4; ++i)
#pragma unroll
      for (int r = 0; r < 4; ++r) {
        const float v = acc[i][j][r];
        s[r] += v;
        q[r] += v * v;
      }
#pragma unroll
    for (int st = 1; st <= 8; st <<= 1)
#pragma unroll
      for (int r = 0; r < 4; ++r) {
        s[r] += __shfl_xor(s[r], st);
        q[r] += __shfl_xor(q[r], st);
      }
    if (fr == 0) {
#pragma unroll
      for (int r = 0; r < 4; ++r) {
        atomicAdd(&g.ssum[cb + r], s[r]);
        atomicAdd(&g.ssq[cb + r], q[r]);
      }
    }
  }
}

__global__ __launch_bounds__(256) void gemm_dual(GemmArgs g0, GemmArgs g1, int N) {
  __shared__ u16 As[128 * 32];
  __shared__ u16 Bs[128 * 32];
  gemm_body(blockIdx.z ? g1 : g0, N, As, Bs);
}

// out = A @ W^T + bias, fp32 out, no stats
__global__ __launch_bounds__(256) void gemm_bias(
    const u16* __restrict__ A, const u16* __restrict__ W, float* __restrict__ C,
    int N, int K, const float* __restrict__ bias) {
  __shared__ u16 As[128 * 32];
  __shared__ u16 Bs[128 * 32];
  const int tid = threadIdx.x;
  const int lane = tid & 63;
  const int wave = tid >> 6;
  const int wm = (wave >> 1) << 6;
  const int wn = (wave & 1) << 6;
  const int m0 = blockIdx.y * 128;
  const int n0 = blockIdx.x * 128;
  const u16* Ab = A + (size_t)m0 * K;
  const u16* Wb = W + (size_t)n0 * K;
  const size_t soff = (size_t)(tid >> 2) * K + ((tid & 3) << 3);
  const size_t soff2 = soff + (size_t)64 * K;
  const int fr = lane & 15;
  const int fq = lane >> 4;
  const int aoff = fr * 32 + fq * 8;

  floatx4 acc[4][4] = {};
  for (int k0 = 0; k0 < K; k0 += 32) {
    __syncthreads();
    GLDS(Ab + soff + k0, &As[tid * 8]);
    GLDS(Ab + soff2 + k0, &As[tid * 8 + 2048]);
    GLDS(Wb + soff + k0, &Bs[tid * 8]);
    GLDS(Wb + soff2 + k0, &Bs[tid * 8 + 2048]);
    __syncthreads();
    bf16x8 af[4], bfv[4];
#pragma unroll
    for (int i = 0; i < 4; ++i) af[i] = *(const bf16x8*)&As[(wm + i * 16) * 32 + aoff];
#pragma unroll
    for (int j = 0; j < 4; ++j) bfv[j] = *(const bf16x8*)&Bs[(wn + j * 16) * 32 + aoff];
#pragma unroll
    for (int i = 0; i < 4; ++i)
#pragma unroll
      for (int j = 0; j < 4; ++j)
        acc[i][j] = __builtin_amdgcn_mfma_f32_16x16x32_bf16(bfv[j], af[i], acc[i][j], 0, 0, 0);
  }
#pragma unroll
  for (int i = 0; i < 4; ++i) {
    const size_t row = (size_t)(m0 + wm + i * 16 + fr);
#pragma unroll
    for (int j = 0; j < 4; ++j) {
      const int cb = n0 + wn + j * 16 + fq * 4;
      const floatx4 bv = *(const floatx4*)&bias[cb];
      floatx4 o;
#pragma unroll
      for (int r = 0; r < 4; ++r) o[r] = acc[i][j][r] + bv[r];
      *(floatx4*)&C[row * N + cb] = o;
    }
  }
}

// ---- fused input conversions: inp pad + h0 cast + stats zero ----
__global__ void conv_in_k(const float* __restrict__ x, const float* __restrict__ y,
                          u16* __restrict__ inpb, const float4* __restrict__ h04,
                          u16x4* __restrict__ h0b4, float* __restrict__ stats) {
  const int blk = blockIdx.x;
  const int tid = threadIdx.x;
  if (blk < 18432) {  // B*288/256
    const int idx = blk * 256 + tid;
    const int b = idx / 288;
    const int c = idx - b * 288;
    float v = 0.f;
    if (c < 256) v = x[b * 256 + c];
    else if (c == 256) v = y[b];
    inpb[idx] = f2b(v);
  } else if (blk < 18432 + 16384) {  // 2*B*H/4 float4s
    const int id = (blk - 18432) * 256 + tid;
    const float4 v = h04[id];
    u16x4 r;
    r.x = f2b(v.x); r.y = f2b(v.y); r.z = f2b(v.z); r.w = f2b(v.w);
    h0b4[id] = r;
  } else {  // zero 8*2048 stats floats (64 blocks)
    const int id = (blk - 18432 - 16384) * 256 + tid;
    stats[id] = 0.f;
  }
}

// ---- fused weight conversions ----
__global__ void conv_w_k(const float* __restrict__ Wx0, u16* __restrict__ wx0b,
                         const float4* __restrict__ Wh0, u16x4* __restrict__ wh0b,
                         const float4* __restrict__ Wx1, u16x4* __restrict__ wx1b,
                         const float4* __restrict__ Wh1, u16x4* __restrict__ wh1b,
                         const float4* __restrict__ Wo, u16x4* __restrict__ wob) {
  const int blk = blockIdx.x;
  const int tid = threadIdx.x;
  if (blk < 2304) {  // 2048*288/256 pad kernel
    const int idx = blk * 256 + tid;
    const int r = idx / 288;
    const int c = idx - r * 288;
    wx0b[idx] = f2b(c < 257 ? Wx0[r * 257 + c] : 0.f);
    return;
  }
  const float4* src;
  u16x4* dst;
  int rel = blk - 2304;
  if (rel < 1024) { src = Wh0; dst = wh0b; }
  else if (rel < 2048) { src = Wx1; dst = wx1b; rel -= 1024; }
  else if (rel < 3072) { src = Wh1; dst = wh1b; rel -= 2048; }
  else { src = Wo; dst = wob; rel -= 3072; }
  const int id = rel * 256 + tid;
  const float4 v = src[id];
  u16x4 r;
  r.x = f2b(v.x); r.y = f2b(v.y); r.z = f2b(v.z); r.w = f2b(v.w);
  dst[id] = r;
}

// stats layout per layer: [sum_x, sq_x, sum_h, sq_h] each 2048
// coef layout per layer:  [ax, ah, cb] each 2048
__global__ void coef_k(const float* __restrict__ st, const float* __restrict__ gx,
                       const float* __restrict__ bx, const float* __restrict__ gh,
                       const float* __restrict__ bh, float* __restrict__ cf, float invB) {
  const int j = blockIdx.x * 256 + threadIdx.x;  // 2048
  const float mx = st[j] * invB;
  const float vx = st[2048 + j] * invB - mx * mx;
  const float ax = gx[j] * rsqrtf(vx + 1e-5f);
  const float mh = st[4096 + j] * invB;
  const float vh = st[6144 + j] * invB - mh * mh;
  const float ah = gh[j] * rsqrtf(vh + 1e-5f);
  cf[j] = ax;
  cf[2048 + j] = ah;
  cf[4096 + j] = bx[j] - mx * ax + bh[j] - mh * ah;
}

// fused BN-affine + LSTM cell; 2 columns per thread
__global__ void cell_k(const u16* __restrict__ Zx, const u16* __restrict__ Zh,
                       const float* __restrict__ coef, const float* __restrict__ cin,
                       float* __restrict__ hout, float* __restrict__ cout,
                       u16* __restrict__ hb) {
  const int idx = blockIdx.x * 256 + threadIdx.x;  // B*256
  const int b = idx >> 8;
  const int j2 = (idx & 255) << 1;
  const size_t rb = (size_t)b << 11;
  float gv[4][2];
#pragma unroll
  for (int g = 0; g < 4; ++g) {
    const int col = (g << 9) + j2;
    const u32 zx = *(const u32*)(Zx + rb + col);
    const u32 zh = *(const u32*)(Zh + rb + col);
#pragma unroll
    for (int t = 0; t < 2; ++t) {
      const float zxv = b2f((u16)(zx >> (16 * t)));
      const float zhv = b2f((u16)(zh >> (16 * t)));
      gv[g][t] = coef[col + t] * zxv + coef[2048 + col + t] * zhv + coef[4096 + col + t];
    }
  }
  const size_t ob = ((size_t)b << 9) + j2;
  const float2 cp = *(const float2*)(cin + ob);
  float cn[2], hn[2];
#pragma unroll
  for (int t = 0; t < 2; ++t) {
    const float cprev = t ? cp.y : cp.x;
    const float cc = sigf(gv[0][t]) * cprev + sigf(gv[1][t]) * tanhfast(gv[3][t]);
    cn[t] = cc;
    hn[t] = sigf(gv[2][t]) * tanhfast(cc);
  }
  *(float2*)(cout + ob) = make_float2(cn[0], cn[1]);
  *(float2*)(hout + ob) = make_float2(hn[0], hn[1]);
  *(u32*)(hb + ob) = (u32)f2b(hn[0]) | ((u32)f2b(hn[1]) << 16);
}

extern "C" void kernel_launch(void* const* d_in, const int* in_sizes, int n_in,
                              void* d_out, int out_size, void* d_ws, size_t ws_size,
                              hipStream_t stream) {
  (void)in_sizes; (void)n_in; (void)out_size; (void)ws_size;
  constexpr int B = 16384, H = 512, G = 2048, KP = 288, K1 = 512, NOUT = 256;

  const float* x = (const float*)d_in[0];
  const float* y = (const float*)d_in[1];
  const float* h0 = (const float*)d_in[2];
  const float* c0 = (const float*)d_in[3];
  const float* Wx0 = (const float*)d_in[4];
  const float* Wh0 = (const float*)d_in[5];
  const float* gx0 = (const float*)d_in[6];
  const float* bx0 = (const float*)d_in[7];
  const float* gh0 = (const float*)d_in[8];
  const float* bh0 = (const float*)d_in[9];
  const float* Wx1 = (const float*)d_in[10];
  const float* Wh1 = (const float*)d_in[11];
  const float* gx1 = (const float*)d_in[12];
  const float* bx1 = (const float*)d_in[13];
  const float* gh1 = (const float*)d_in[14];
  const float* bh1 = (const float*)d_in[15];
  const float* Wo = (const float*)d_in[16];
  const float* bo = (const float*)d_in[17];

  char* p = (char*)d_ws;
  u16* Zx = (u16*)p;   p += (size_t)B * G * 2;
  u16* Zh = (u16*)p;   p += (size_t)B * G * 2;
  u16* h0b = (u16*)p;  p += (size_t)2 * B * H * 2;
  u16* h1b = (u16*)p;  p += (size_t)B * H * 2;   // reused for h2 bf16
  u16* inpb = (u16*)p; p += (size_t)B * KP * 2;
  u16* wx0b = (u16*)p; p += (size_t)G * KP * 2;
  u16* wh0b = (u16*)p; p += (size_t)G * K1 * 2;
  u16* wx1b = (u16*)p; p += (size_t)G * K1 * 2;
  u16* wh1b = (u16*)p; p += (size_t)G * K1 * 2;
  u16* wob = (u16*)p;  p += (size_t)NOUT * K1 * 2;
  float* stats = (float*)p; p += (size_t)8 * G * 4;
  float* coef = (float*)p;  p += (size_t)6 * G * 4;

  float* out_o = (float*)d_out;                     // [B,256]
  float* h_o = out_o + (size_t)B * NOUT;            // [2,B,512]
  float* c_o = h_o + (size_t)2 * B * H;             // [2,B,512]

  conv_in_k<<<18432 + 16384 + 64, 256, 0, stream>>>(x, y, inpb, (const float4*)h0,
                                                    (u16x4*)h0b, stats);
  conv_w_k<<<2304 + 3200, 256, 0, stream>>>(Wx0, wx0b, (const float4*)Wh0, (u16x4*)wh0b,
                                            (const float4*)Wx1, (u16x4*)wx1b,
                                            (const float4*)Wh1, (u16x4*)wh1b,
                                            (const float4*)Wo, (u16x4*)wob);

  const dim3 blk(256);
  const dim3 gdual(G / 128, B / 128, 2);

  // layer 0
  {
    GemmArgs ga{inpb, wx0b, Zx, KP, stats + 0 * G, stats + 1 * G};
    GemmArgs gb{h0b, wh0b, Zh, K1, stats + 2 * G, stats + 3 * G};
    gemm_dual<<<gdual, blk, 0, stream>>>(ga, gb, G);
  }
  coef_k<<<G / 256, 256, 0, stream>>>(stats, gx0, bx0, gh0, bh0, coef, 1.f / B);
  cell_k<<<B, 256, 0, stream>>>(Zx, Zh, coef, c0, h_o, c_o, h1b);

  // layer 1
  {
    GemmArgs ga{h1b, wx1b, Zx, K1, stats + 4 * G, stats + 5 * G};
    GemmArgs gb{h0b + (size_t)B * H, wh1b, Zh, K1, stats + 6 * G, stats + 7 * G};
    gemm_dual<<<gdual, blk, 0, stream>>>(ga, gb, G);
  }
  coef_k<<<G / 256, 256, 0, stream>>>(stats + 4 * G, gx1, bx1, gh1, bh1, coef + 3 * G, 1.f / B);
  cell_k<<<B, 256, 0, stream>>>(Zx, Zh, coef + 3 * G, c0 + (size_t)B * H,
                                h_o + (size_t)B * H, c_o + (size_t)B * H, h1b);

  // output projection
  const dim3 gout(NOUT / 128, B / 128, 1);
  gemm_bias<<<gout, blk, 0, stream>>>(h1b, wob, out_o, NOUT, K1, bo);
}